// Round 5
// baseline (4577.700 us; speedup 1.0000x reference)
//
#include <hip/hip_runtime.h>
#include <hip/hip_bf16.h>
#include <cmath>

// Problem dims
#define Bb 128
#define Tt 512
#define Ii 512
#define Hh 2048
#define Oo 512
#define REC_GRID 256

typedef __bf16 bf16_t;
typedef __bf16 bf16x8 __attribute__((ext_vector_type(8)));
typedef __bf16 bf16x4 __attribute__((ext_vector_type(4)));
typedef float  f32x4_t __attribute__((ext_vector_type(4)));
typedef unsigned long long u64;

static __device__ __forceinline__ bf16_t to_b(float v){ return (bf16_t)v; }
static __device__ __forceinline__ float  b2f(unsigned short u){ unsigned x = ((unsigned)u)<<16; return __builtin_bit_cast(float, x); }
static __device__ __forceinline__ unsigned short f2bbits(float v){ return __builtin_bit_cast(unsigned short, to_b(v)); }

// async global->LDS, 16B per lane, linear LDS dest (wave-uniform base + lane*16)
static __device__ __forceinline__ void gl_lds16(const void* g, void* l){
  __builtin_amdgcn_global_load_lds((const __attribute__((address_space(1))) void*)g,
                                   (__attribute__((address_space(3))) void*)l, 16, 0, 0);
}

// ---------- small prep kernels ----------
__global__ __launch_bounds__(256) void k_f2b(bf16_t* __restrict__ dst, const float* __restrict__ src){
  size_t i = ((size_t)blockIdx.x*256 + threadIdx.x)*4;
  float4 v = *(const float4*)(src + i);
  bf16x4 o; o[0]=to_b(v.x); o[1]=to_b(v.y); o[2]=to_b(v.z); o[3]=to_b(v.w);
  *(bf16x4*)(dst + i) = o;
}

__global__ __launch_bounds__(256) void k_init_h0(const float* __restrict__ hi_w, const float* __restrict__ hi_b,
                                                 bf16_t* __restrict__ h0b){
  int i = blockIdx.x*256 + threadIdx.x;           // [0, H)
  bf16_t vb = to_b(hi_w[i] + hi_b[i]);
  for (int b=0;b<Bb;++b) h0b[(size_t)b*Hh + i] = vb;
}

__global__ __launch_bounds__(256) void k_convert_x(const float* __restrict__ x, bf16_t* __restrict__ x_tm){
  size_t idx = ((size_t)blockIdx.x*256 + threadIdx.x)*8;
  int    i0  = (int)(idx % Ii);
  size_t m   = idx / Ii;                          // m = t*B + b
  int    t   = (int)(m / Bb), b = (int)(m % Bb);
  const float* s = x + ((size_t)b*Tt + t)*Ii + i0;
  float4 v0 = *(const float4*)s, v1 = *(const float4*)(s+4);
  bf16x8 o;
  o[0]=to_b(v0.x); o[1]=to_b(v0.y); o[2]=to_b(v0.z); o[3]=to_b(v0.w);
  o[4]=to_b(v1.x); o[5]=to_b(v1.y); o[6]=to_b(v1.z); o[7]=to_b(v1.w);
  *(bf16x8*)(x_tm + idx) = o;
}

// ---------- GEMM building blocks (encoder / decoder) ----------
template<int ROWS, int KB>
static __device__ __forceinline__ void stage(const bf16_t* __restrict__ g, long ld, long row0, int k0,
                                             char* __restrict__ ldsT){
  constexpr int SLOTS = KB/8;
  constexpr int PT    = ROWS*SLOTS/256;
  #pragma unroll
  for (int j=0;j<PT;++j){
    int c    = threadIdx.x + 256*j;
    int row  = c / SLOTS, slot = c % SLOTS;
    uint4 v  = *(const uint4*)(g + (row0+row)*ld + k0 + slot*8);
    *(uint4*)(ldsT + row*(KB*2) + ((slot*16) ^ ((row&7)<<4))) = v;
  }
}

template<int KB>
static __device__ __forceinline__ bf16x8 frag(const char* __restrict__ ldsT, int row, int kk, int lane){
  int kbyte = kk*64 + ((lane>>4)<<4);
  return *(const bf16x8*)(ldsT + row*(KB*2) + (kbyte ^ ((row&7)<<4)));
}

template<int EPI>
__global__ __launch_bounds__(256) void gemm128(const bf16_t* __restrict__ A, long lda,
                                               const bf16_t* __restrict__ Bw, long ldb,
                                               const float* __restrict__ bias,
                                               void* __restrict__ Cout, long ldc, int K){
  constexpr int TM=128, TN=128, KB=64;
  __shared__ char lds[(TM+TN)*KB*2];
  char* ldsA = lds;
  char* ldsB = lds + TM*KB*2;
  long m0 = (long)blockIdx.x * TM;
  long n0 = (long)blockIdx.y * TN;
  int w = threadIdx.x >> 6, lane = threadIdx.x & 63;
  int wm = w >> 1, wn = w & 1;
  f32x4_t acc[4][4] = {};
  for (int k0=0;k0<K;k0+=KB){
    __syncthreads();
    stage<TM,KB>(A,  lda, m0, k0, ldsA);
    stage<TN,KB>(Bw, ldb, n0, k0, ldsB);
    __syncthreads();
    #pragma unroll
    for (int kk=0;kk<KB/32;++kk){
      bf16x8 af[4], bfv[4];
      #pragma unroll
      for (int f=0;f<4;++f){ int r = wm*64 + f*16 + (lane&15); af[f]  = frag<KB>(ldsA, r, kk, lane); }
      #pragma unroll
      for (int f=0;f<4;++f){ int r = wn*64 + f*16 + (lane&15); bfv[f] = frag<KB>(ldsB, r, kk, lane); }
      #pragma unroll
      for (int i=0;i<4;++i)
        #pragma unroll
        for (int j=0;j<4;++j)
          acc[i][j] = __builtin_amdgcn_mfma_f32_16x16x32_bf16(af[i], bfv[j], acc[i][j], 0,0,0);
    }
  }
  #pragma unroll
  for (int i=0;i<4;++i)
    #pragma unroll
    for (int j=0;j<4;++j)
      #pragma unroll
      for (int e=0;e<4;++e){
        long row = m0 + wm*64 + i*16 + ((lane>>4)<<2) + e;
        long col = n0 + wn*64 + j*16 + (lane&15);
        float v = acc[i][j][e] + bias[col];
        if (EPI==0) ((bf16_t*)Cout)[row*ldc + col] = to_b(v);
        else        ((float*) Cout)[row*ldc + col] = v;
      }
}

// ---------- persistent recurrence kernel ----------
// 4 groups of 64 blocks; block (g,n): batches 32g..+31, H-cols 32n..+31.
// W (128 KB) lives in LDS in MFMA-FRAGMENT ORDER: 16B chunk (hh,kkg,lane) =
// W[n0+hh*16+(lane&15)][kkg*32+(lane>>4)*8 ..+8] at offset ((hh*64+kkg)*64+lane)*16.
// A (h_prev) staged per step via global_load_lds into double-buffered 16 KB
// chunks, ALSO in fragment order (pre-scattered per-lane global source, linear
// LDS dest). Every frag ds_read_b128 is base_uniform + lane*16: conflict-free.
// Waves split K 4-ways (kk%4==w), each accumulates all 4 quadrants of the
// 32x32 tile; 16 KB LDS reduction hands quadrant w to wave w (each fragment
// read exactly once per step). enc-read/h-write: cooperative coalesced u64
// agent atomics exchanged through LDS. Barrier: per-(group,step) counter.
__global__ __launch_bounds__(256, 1) void rec_persist(
    const bf16_t* __restrict__ h0b, const bf16_t* __restrict__ W,
    bf16_t* __restrict__ EH, float* __restrict__ hfinal,
    const float* __restrict__ rec_b, const float* __restrict__ hi_w, const float* __restrict__ hi_b,
    const float* __restrict__ dtp, const float* __restrict__ ap,
    unsigned* __restrict__ cnt)
{
  __shared__ uint4 lds4[163840/16];      // 160 KB: W(128K) + 2x16K A chunks
  char* lds = (char*)lds4;
  char* Wb  = lds;
  char* Ab0 = lds + 131072;
  char* Ab1 = lds + 147456;

  const int bid = blockIdx.x;
  const int g   = bid & 3;               // batch group (clusters on XCD pairs)
  const int n   = bid >> 2;              // H tile 0..63
  const int m0  = g * 32;
  const int n0  = n * 32;
  unsigned* gcnt = cnt + g*512;
  const int tid = threadIdx.x, w = tid >> 6, lane = tid & 63;
  const int boff = (w & 1) * 16, hoff = (w >> 1) * 16;   // this wave's final quadrant

  // one-time W staging in fragment order (write = tid*16 linear, conflict-free)
  for (int it = 0; it < 32; ++it){
    int cid = it*256 + tid;
    int lc  = cid & 63, kkg = (cid >> 6) & 63, hh = cid >> 12;
    uint4 v = *(const uint4*)(W + (size_t)(n0 + hh*16 + (lc&15))*Hh + kkg*32 + ((lc>>4)<<3));
    *(uint4*)(Wb + (size_t)cid*16) = v;
  }
  __syncthreads();

  const float s  = 1.f/(1.f + __expf(-dtp[0]));
  const float av = ap[0];
  const int   batch = m0 + boff + (lane & 15);          // C col = lane&15 -> batch
  const int   hcol0 = n0 + hoff + ((lane >> 4) << 2);   // C row = (lane>>4)*4+e -> H col
  const int   lslot = (boff + (lane & 15))*8 + (w>>1)*4 + (lane>>4);
  float rb[4], hm[4];
  #pragma unroll
  for (int e=0;e<4;++e){ rb[e] = rec_b[hcol0+e]; hm[e] = hi_w[hcol0+e] + hi_b[hcol0+e]; }

  // staging: per-lane global scatter so LDS lands in fragment order
  const size_t st_base = (size_t)(m0 + (lane & 15))*Hh + ((lane >> 4) << 3);
  // cooperative enc/h addressing (thread tid -> batch tid>>3, 4-col block tid&7)
  const int co_b = m0 + (tid >> 3);
  const int co_c = n0 + (tid & 7)*4;

  for (int t = 0; t < Tt; ++t){
    const bf16_t* Asrc = (t==0) ? h0b : (EH + (size_t)(t-1)*(Bb*Hh));
    bf16_t* EHt = EH + (size_t)t*(Bb*Hh);

    // issue chunk 0 staging; cooperative enc load into reg
    #pragma unroll
    for (int i=0;i<4;++i){
      int sl = w*4 + i, hb = sl >> 3, kkl = sl & 7;
      gl_lds16(Asrc + st_base + (size_t)hb*(16*Hh) + kkl*32, Ab0 + sl*1024);
    }
    u64 ecv = __hip_atomic_load((const u64*)(EHt + (size_t)co_b*Hh + co_c),
                                __ATOMIC_RELAXED, __HIP_MEMORY_SCOPE_AGENT);

    f32x4_t a00={0.f,0.f,0.f,0.f}, a01=a00, a10=a00, a11=a00;  // [hh][hb] partials
    #pragma unroll
    for (int c=0;c<8;++c){
      __syncthreads();                   // chunk c staged (vmcnt drained)
      if (c < 7){
        char* dst = ((c+1)&1) ? Ab1 : Ab0;
        #pragma unroll
        for (int i=0;i<4;++i){
          int sl = w*4 + i, hb = sl >> 3, kkl = sl & 7;
          gl_lds16(Asrc + st_base + (size_t)hb*(16*Hh) + (c+1)*256 + kkl*32, dst + sl*1024);
        }
      }
      const char* ab = (c&1) ? Ab1 : Ab0;
      #pragma unroll
      for (int u=0;u<2;++u){
        int kkl = w + u*4;               // this wave's kk%4==w slice
        int kkg = c*8 + kkl;
        bf16x8 wa0 = *(const bf16x8*)(Wb +          (size_t)kkg*1024 + lane*16);
        bf16x8 wa1 = *(const bf16x8*)(Wb + 65536 + (size_t)kkg*1024 + lane*16);
        bf16x8 ha0 = *(const bf16x8*)(ab +          kkl*1024 + lane*16);
        bf16x8 ha1 = *(const bf16x8*)(ab + 8192  +  kkl*1024 + lane*16);
        a00 = __builtin_amdgcn_mfma_f32_16x16x32_bf16(wa0, ha0, a00, 0,0,0);
        a01 = __builtin_amdgcn_mfma_f32_16x16x32_bf16(wa0, ha1, a01, 0,0,0);
        a10 = __builtin_amdgcn_mfma_f32_16x16x32_bf16(wa1, ha0, a10, 0,0,0);
        a11 = __builtin_amdgcn_mfma_f32_16x16x32_bf16(wa1, ha1, a11, 0,0,0);
      }
    }

    // cross-wave K-reduction: wave w ends up owning quadrant q=w (hh=w>>1, hb=w&1)
    __syncthreads();                     // all chunk reads done; Ab0/Ab1 reusable
    char* red = Ab0;                     // 16 KB: (srcwave, q, lane) 16B chunks
    u64*  xb  = (u64*)Ab1;               // 2 KB exchange
    *(f32x4_t*)(red + ((w*4+0)*64 + lane)*16) = a00;
    *(f32x4_t*)(red + ((w*4+1)*64 + lane)*16) = a01;
    *(f32x4_t*)(red + ((w*4+2)*64 + lane)*16) = a10;
    *(f32x4_t*)(red + ((w*4+3)*64 + lane)*16) = a11;
    xb[tid] = ecv;
    __syncthreads();
    f32x4_t fa = *(const f32x4_t*)(red + ((0*4+w)*64 + lane)*16);
    fa = fa + *(const f32x4_t*)(red + ((1*4+w)*64 + lane)*16);
    fa = fa + *(const f32x4_t*)(red + ((2*4+w)*64 + lane)*16);
    fa = fa + *(const f32x4_t*)(red + ((3*4+w)*64 + lane)*16);

    u64 ev = xb[lslot];
    u64 ov = 0;
    #pragma unroll
    for (int e=0;e<4;++e){
      float enc = b2f((unsigned short)(ev >> (16*e)));
      float pre = enc + av*(fa[e] + rb[e]);
      float th  = 1.f - 2.f/(__expf(2.f*pre) + 1.f);   // tanh
      hm[e] = (1.f - s)*hm[e] + s*th;
      ov |= ((u64)f2bbits(hm[e])) << (16*e);
    }
    xb[lslot] = ov;                      // same thread reads then writes its own slot
    __syncthreads();
    u64 hv = xb[tid];
    __hip_atomic_store((u64*)(EHt + (size_t)co_b*Hh + co_c), hv,
                       __ATOMIC_RELAXED, __HIP_MEMORY_SCOPE_AGENT);
    __syncthreads();                     // drains all waves' store acks

    // group barrier: one counter per (group, step)
    if (tid == 0){
      __hip_atomic_fetch_add(gcnt + t, 1u, __ATOMIC_RELAXED, __HIP_MEMORY_SCOPE_AGENT);
      while (__hip_atomic_load(gcnt + t, __ATOMIC_RELAXED, __HIP_MEMORY_SCOPE_AGENT) < 64u) {}
    }
    __syncthreads();
  }

  // final hidden (f32) -> out tail
  #pragma unroll
  for (int e=0;e<4;++e) hfinal[(size_t)batch*Hh + hcol0 + e] = hm[e];
}

// ---------- launch ----------
extern "C" void kernel_launch(void* const* d_in, const int* in_sizes, int n_in,
                              void* d_out, int out_size, void* d_ws, size_t ws_size,
                              hipStream_t stream){
  const float* x     = (const float*)d_in[0];
  const float* dt    = (const float*)d_in[1];
  const float* a     = (const float*)d_in[2];
  const float* enc_w = (const float*)d_in[3];
  const float* enc_b = (const float*)d_in[4];
  const float* rec_w = (const float*)d_in[5];
  const float* rec_b = (const float*)d_in[6];
  const float* dec_w = (const float*)d_in[7];
  const float* dec_b = (const float*)d_in[8];
  const float* hi_w  = (const float*)d_in[9];
  const float* hi_b  = (const float*)d_in[10];
  float* out = (float*)d_out;

  // workspace carve-out (~333 MB)
  char* ws = (char*)d_ws;
  size_t off = 0;
  auto carve = [&](size_t bytes)->char*{ char* p = ws + off; off += (bytes + 255) & ~(size_t)255; return p; };
  bf16_t* x_tm   = (bf16_t*)carve((size_t)Tt*Bb*Ii*2);   // 64 MB
  bf16_t* EH     = (bf16_t*)carve((size_t)Tt*Bb*Hh*2);   // 256 MB  enc -> h history
  bf16_t* h0b    = (bf16_t*)carve((size_t)Bb*Hh*2);
  bf16_t* enc_wb = (bf16_t*)carve((size_t)Hh*Ii*2);
  bf16_t* rec_wb = (bf16_t*)carve((size_t)Hh*Hh*2);
  bf16_t* dec_wb = (bf16_t*)carve((size_t)Oo*Hh*2);
  unsigned* cnt  = (unsigned*)carve(4*512*4);             // per-(group,step) counters
  if (off > ws_size) return;  // diagnostic: leaves output zeroed

  // reset barrier counters every call (ws is not re-poisoned between replays)
  hipMemsetAsync(cnt, 0, 4*512*4, stream);

  // weights -> bf16
  k_f2b<<<(Hh*Ii)/1024, 256, 0, stream>>>(enc_wb, enc_w);
  k_f2b<<<(Hh*Hh)/1024, 256, 0, stream>>>(rec_wb, rec_w);
  k_f2b<<<(Oo*Hh)/1024, 256, 0, stream>>>(dec_wb, dec_w);
  k_init_h0<<<Hh/256, 256, 0, stream>>>(hi_w, hi_b, h0b);
  k_convert_x<<<((size_t)Tt*Bb*Ii/8)/256, 256, 0, stream>>>(x, x_tm);

  // encoder: EH[t*B+b, h] = x_tm @ enc_w^T + enc_b   (M=65536, K=512, N=2048)
  gemm128<0><<<dim3((Tt*Bb)/128, Hh/128), 256, 0, stream>>>(x_tm, Ii, enc_wb, Ii, enc_b, EH, Hh, Ii);

  // recurrence: one persistent cooperative kernel, 512 steps, per-group counters
  {
    float* hfinal = out + (size_t)Tt*Bb*Oo;
    void* args[] = { (void*)&h0b, (void*)&rec_wb, (void*)&EH, (void*)&hfinal,
                     (void*)&rec_b, (void*)&hi_w, (void*)&hi_b, (void*)&dt, (void*)&a,
                     (void*)&cnt };
    hipLaunchCooperativeKernel((const void*)rec_persist, dim3(REC_GRID), dim3(256), args, 0, stream);
  }

  // decoder: out[t*B+b, o] = EH @ dec_w^T + dec_b   (M=65536, K=2048, N=512)
  gemm128<1><<<dim3((Tt*Bb)/128, Oo/128), 256, 0, stream>>>(EH, Hh, dec_wb, Hh, dec_b, out, Oo, Hh);
}